// Round 1
// baseline (2991.270 us; speedup 1.0000x reference)
//
#include <hip/hip_runtime.h>
#include <math.h>

#define F 128   // F_IN == F_HID == F_OUT == 128
#define N_GRAPHS 256

// ---------------------------------------------------------------------------
// K0: detect index dtype. If batch (reinterpreted as int32) has nonzero last
// element -> int32 (flag=1). If int64, odd words are high words == 0 (flag=0).
// ---------------------------------------------------------------------------
__global__ void detect_kernel(const int* __restrict__ batch_raw, int nN,
                              int* __restrict__ flag) {
    if (threadIdx.x == 0 && blockIdx.x == 0) {
        *flag = (batch_raw[nN - 1] != 0) ? 1 : 0;
    }
}

// ---------------------------------------------------------------------------
// K1: convert indices to int32 into ws; also init deg = 1.0 (self-loop).
// ---------------------------------------------------------------------------
__global__ __launch_bounds__(256) void convert_kernel(
    const int* __restrict__ ei_raw, const int* __restrict__ batch_raw,
    int nE, int nN, const int* __restrict__ flag,
    int* __restrict__ row32, int* __restrict__ col32,
    int* __restrict__ batch32, float* __restrict__ deg) {
    int i = blockIdx.x * 256 + threadIdx.x;
    bool is32 = (*flag != 0);
    if (i < nE) {
        if (is32) {
            row32[i] = ei_raw[i];
            col32[i] = ei_raw[nE + i];
        } else {
            const long long* l = (const long long*)ei_raw;
            row32[i] = (int)l[i];
            col32[i] = (int)l[nE + i];
        }
    }
    if (i < nN) {
        batch32[i] = is32 ? batch_raw[i] : (int)((const long long*)batch_raw)[i];
        deg[i] = 1.0f;  // self-loop
    }
}

// ---------------------------------------------------------------------------
// K2: in-degree via atomics over col.
// ---------------------------------------------------------------------------
__global__ __launch_bounds__(256) void deg_scatter_kernel(
    const int* __restrict__ col32, float* __restrict__ deg, int nE) {
    int e = blockIdx.x * 256 + threadIdx.x;
    if (e < nE) atomicAdd(&deg[col32[e]], 1.0f);
}

// ---------------------------------------------------------------------------
// K3: dinv = rsqrt(deg)   (deg >= 1 always, self-loop included)
// ---------------------------------------------------------------------------
__global__ __launch_bounds__(256) void dinv_kernel(
    const float* __restrict__ deg, float* __restrict__ dinv, int nN) {
    int n = blockIdx.x * 256 + threadIdx.x;
    if (n < nN) dinv[n] = rsqrtf(deg[n]);
}

// ---------------------------------------------------------------------------
// K4: h = x @ W1 ; agg = b1 + dinv^2 * h   (self-loop term folded in)
// Tile: 64 rows x 128 cols per block, full K=128. W1 + x-tile in LDS (96 KB).
// 256 threads: 8 node-groups x 32 feature-threads; thread -> 8 nodes x float4.
// ---------------------------------------------------------------------------
__global__ __launch_bounds__(256) void gemm1_kernel(
    const float* __restrict__ x, const float* __restrict__ W1,
    const float* __restrict__ b1, const float* __restrict__ dinv,
    float* __restrict__ h, float* __restrict__ agg, int nN) {
    __shared__ float ws[F * F];      // 64 KB
    __shared__ float xs[64 * F];     // 32 KB
    int t = threadIdx.x;
    int row0 = blockIdx.x * 64;

    // load W1 (16384 floats) as float4
    {
        const float4* w4 = (const float4*)W1;
        float4* ws4 = (float4*)ws;
        for (int i = t; i < F * F / 4; i += 256) ws4[i] = w4[i];
    }
    // load x tile (64 x 128) as float4, zero-padded past nN
    {
        float4* xs4 = (float4*)xs;
        for (int i = t; i < 64 * F / 4; i += 256) {
            int r = i >> 5;  // 32 float4 per row
            int gr = row0 + r;
            float4 v = make_float4(0.f, 0.f, 0.f, 0.f);
            if (gr < nN) v = ((const float4*)x)[(size_t)gr * 32 + (i & 31)];
            xs4[i] = v;
        }
    }
    __syncthreads();

    int ft = t & 31;   // feature thread: cols ft*4 .. ft*4+3
    int ng = t >> 5;   // node group: rows ng*8 .. ng*8+7
    float4 acc[8];
#pragma unroll
    for (int i = 0; i < 8; ++i) acc[i] = make_float4(0.f, 0.f, 0.f, 0.f);

    const float4* wsr = (const float4*)ws;
    for (int k = 0; k < F; ++k) {
        float4 wv = wsr[k * 32 + ft];
#pragma unroll
        for (int i = 0; i < 8; ++i) {
            float xv = xs[(ng * 8 + i) * F + k];
            acc[i].x += xv * wv.x;
            acc[i].y += xv * wv.y;
            acc[i].z += xv * wv.z;
            acc[i].w += xv * wv.w;
        }
    }

    float4 bv = ((const float4*)b1)[ft];
#pragma unroll
    for (int i = 0; i < 8; ++i) {
        int gr = row0 + ng * 8 + i;
        if (gr < nN) {
            float di = dinv[gr];
            float s = di * di;
            ((float4*)h)[(size_t)gr * 32 + ft] = acc[i];
            float4 a;
            a.x = bv.x + s * acc[i].x;
            a.y = bv.y + s * acc[i].y;
            a.z = bv.z + s * acc[i].z;
            a.w = bv.w + s * acc[i].w;
            ((float4*)agg)[(size_t)gr * 32 + ft] = a;
        }
    }
}

// ---------------------------------------------------------------------------
// K5: edge scatter: agg[col] += h[row] * dinv[row]*dinv[col]
// 32 lanes per edge (float4 each), 8 edges per 256-thread block.
// ---------------------------------------------------------------------------
__global__ __launch_bounds__(256) void edge_scatter_kernel(
    const int* __restrict__ row32, const int* __restrict__ col32,
    const float* __restrict__ dinv, const float* __restrict__ h,
    float* __restrict__ agg, int nE) {
    long long gid = (long long)blockIdx.x * 256 + threadIdx.x;
    int e = (int)(gid >> 5);
    if (e >= nE) return;
    int sub = (int)(gid & 31);
    int r = row32[e];
    int c = col32[e];
    float w = dinv[r] * dinv[c];
    float4 hv = ((const float4*)h)[(size_t)r * 32 + sub];
    float* a = agg + (size_t)c * F + sub * 4;
    atomicAdd(a + 0, hv.x * w);
    atomicAdd(a + 1, hv.y * w);
    atomicAdd(a + 2, hv.z * w);
    atomicAdd(a + 3, hv.w * w);
}

// ---------------------------------------------------------------------------
// K6: global mean pool with ReLU. batch is sorted -> binary search bounds.
// One block per graph, 128 threads (one per feature).
// ---------------------------------------------------------------------------
__global__ __launch_bounds__(128) void pool_kernel(
    const float* __restrict__ agg, const int* __restrict__ batch32,
    float* __restrict__ pooled, int nN) {
    int g = blockIdx.x;
    __shared__ int bounds[2];
    if (threadIdx.x < 2) {
        int target = g + threadIdx.x;
        int lo = 0, hi = nN;
        while (lo < hi) {
            int mid = (lo + hi) >> 1;
            if (batch32[mid] < target) lo = mid + 1; else hi = mid;
        }
        bounds[threadIdx.x] = lo;
    }
    __syncthreads();
    int lo = bounds[0], hi = bounds[1];
    int j = threadIdx.x;
    float acc = 0.f;
    for (int n = lo; n < hi; ++n) {
        float v = agg[(size_t)n * F + j];
        acc += fmaxf(v, 0.f);
    }
    float cnt = (float)(hi - lo);
    pooled[g * F + j] = acc / fmaxf(cnt, 1.0f);
}

// ---------------------------------------------------------------------------
// K7: out = tanh(pooled @ W2 + b2). One block per graph, 128 threads.
// ---------------------------------------------------------------------------
__global__ __launch_bounds__(128) void final_kernel(
    const float* __restrict__ pooled, const float* __restrict__ W2,
    const float* __restrict__ b2, float* __restrict__ out) {
    int g = blockIdx.x;
    __shared__ float ps[F];
    ps[threadIdx.x] = pooled[g * F + threadIdx.x];
    __syncthreads();
    int j = threadIdx.x;
    float s = b2[j];
    for (int k = 0; k < F; ++k) s += ps[k] * W2[k * F + j];
    out[g * F + j] = tanhf(s);
}

// ---------------------------------------------------------------------------
extern "C" void kernel_launch(void* const* d_in, const int* in_sizes, int n_in,
                              void* d_out, int out_size, void* d_ws, size_t ws_size,
                              hipStream_t stream) {
    const float* x     = (const float*)d_in[0];
    const int*   ei    = (const int*)d_in[1];   // [2][E], dtype sniffed on device
    const int*   batch = (const int*)d_in[2];
    const float* W1    = (const float*)d_in[3];
    const float* b1    = (const float*)d_in[4];
    const float* W2    = (const float*)d_in[5];
    const float* b2    = (const float*)d_in[6];
    float* out = (float*)d_out;

    const int nN = in_sizes[2];          // 100000
    const int nE = in_sizes[1] / 2;      // 1600000

    // workspace layout (16B-aligned slabs)
    char* ws = (char*)d_ws;
    size_t off = 0;
    auto take = [&](size_t bytes) {
        void* p = ws + off;
        off += (bytes + 15) & ~(size_t)15;
        return p;
    };
    float* agg     = (float*)take((size_t)nN * F * 4);
    float* h       = (float*)take((size_t)nN * F * 4);
    float* deg     = (float*)take((size_t)nN * 4);
    float* dinv    = (float*)take((size_t)nN * 4);
    float* pooled  = (float*)take((size_t)N_GRAPHS * F * 4);
    int*   row32   = (int*)take((size_t)nE * 4);
    int*   col32   = (int*)take((size_t)nE * 4);
    int*   batch32 = (int*)take((size_t)nN * 4);
    int*   flag    = (int*)take(4);

    detect_kernel<<<1, 64, 0, stream>>>(batch, nN, flag);

    int covMax = (nE > nN ? nE : nN);
    convert_kernel<<<(covMax + 255) / 256, 256, 0, stream>>>(
        ei, batch, nE, nN, flag, row32, col32, batch32, deg);

    deg_scatter_kernel<<<(nE + 255) / 256, 256, 0, stream>>>(col32, deg, nE);

    dinv_kernel<<<(nN + 255) / 256, 256, 0, stream>>>(deg, dinv, nN);

    gemm1_kernel<<<(nN + 63) / 64, 256, 0, stream>>>(x, W1, b1, dinv, h, agg, nN);

    long long lanes = (long long)nE * 32;
    edge_scatter_kernel<<<(unsigned)((lanes + 255) / 256), 256, 0, stream>>>(
        row32, col32, dinv, h, agg, nE);

    pool_kernel<<<N_GRAPHS, 128, 0, stream>>>(agg, batch32, pooled, nN);

    final_kernel<<<N_GRAPHS, 128, 0, stream>>>(pooled, W2, b2, out);
}

// Round 2
// 492.027 us; speedup vs baseline: 6.0795x; 6.0795x over previous
//
#include <hip/hip_runtime.h>
#include <math.h>

#define F 128   // F_IN == F_HID == F_OUT == 128
#define N_GRAPHS 256

// ---------------------------------------------------------------------------
// K0: detect index dtype. batch is sorted 0..255; last element nonzero as
// int32 word -> int32. If int64, that word is a high word == 0.
// ---------------------------------------------------------------------------
__global__ void detect_kernel(const int* __restrict__ batch_raw, int nN,
                              int* __restrict__ flag) {
    if (threadIdx.x == 0 && blockIdx.x == 0) {
        *flag = (batch_raw[nN - 1] != 0) ? 1 : 0;
    }
}

// ---------------------------------------------------------------------------
// K1: convert batch to int32, zero the per-node edge counts.
// ---------------------------------------------------------------------------
__global__ __launch_bounds__(256) void prep_kernel(
    const int* __restrict__ batch_raw, int nN, const int* __restrict__ flag,
    int* __restrict__ batch32, int* __restrict__ cnt) {
    int i = blockIdx.x * 256 + threadIdx.x;
    if (i < nN) {
        batch32[i] = (*flag) ? batch_raw[i] : (int)((const long long*)batch_raw)[i];
        cnt[i] = 0;
    }
}

// ---------------------------------------------------------------------------
// K2: in-degree counts (int atomics, L2-resident 400KB array).
// ---------------------------------------------------------------------------
__global__ __launch_bounds__(256) void count_kernel(
    const int* __restrict__ ei_raw, int nE, const int* __restrict__ flag,
    int* __restrict__ cnt) {
    int e = blockIdx.x * 256 + threadIdx.x;
    if (e >= nE) return;
    int c = (*flag) ? ei_raw[nE + e]
                    : (int)((const long long*)ei_raw)[nE + e];
    atomicAdd(&cnt[c], 1);
}

// ---------------------------------------------------------------------------
// K3a/b/c: exclusive scan of cnt -> off (3-pass). chunk = 1024 per block.
// ---------------------------------------------------------------------------
__global__ __launch_bounds__(256) void scanA_kernel(
    const int* __restrict__ cnt, int nN, int* __restrict__ blockSum) {
    __shared__ int sd[256];
    int base = blockIdx.x * 1024;
    int t = threadIdx.x;
    int s = 0;
#pragma unroll
    for (int k = 0; k < 4; ++k) {
        int i = base + t * 4 + k;
        if (i < nN) s += cnt[i];
    }
    sd[t] = s;
    __syncthreads();
    for (int st = 128; st > 0; st >>= 1) {
        if (t < st) sd[t] += sd[t + st];
        __syncthreads();
    }
    if (t == 0) blockSum[blockIdx.x] = sd[0];
}

__global__ __launch_bounds__(256) void scanB_kernel(int* __restrict__ blockSum,
                                                    int nB) {
    // nB <= 256 (nN=100000 -> 98 blocks)
    __shared__ int sd[256];
    int t = threadIdx.x;
    int v = (t < nB) ? blockSum[t] : 0;
    sd[t] = v;
    __syncthreads();
    for (int st = 1; st < 256; st <<= 1) {
        int add = (t >= st) ? sd[t - st] : 0;
        __syncthreads();
        sd[t] += add;
        __syncthreads();
    }
    if (t < nB) blockSum[t] = sd[t] - v;  // exclusive
}

__global__ __launch_bounds__(256) void scanC_kernel(
    const int* __restrict__ cnt, int nN, const int* __restrict__ blockOff,
    int* __restrict__ off, int* __restrict__ cursor, float* __restrict__ dinv) {
    __shared__ int sd[256];
    int base = blockIdx.x * 1024;
    int t = threadIdx.x;
    int v[4];
    int s = 0;
#pragma unroll
    for (int k = 0; k < 4; ++k) {
        int i = base + t * 4 + k;
        v[k] = (i < nN) ? cnt[i] : 0;
        s += v[k];
    }
    sd[t] = s;
    __syncthreads();
    for (int st = 1; st < 256; st <<= 1) {
        int add = (t >= st) ? sd[t - st] : 0;
        __syncthreads();
        sd[t] += add;
        __syncthreads();
    }
    int run = blockOff[blockIdx.x] + sd[t] - s;  // exclusive prefix
#pragma unroll
    for (int k = 0; k < 4; ++k) {
        int i = base + t * 4 + k;
        if (i < nN) {
            off[i] = run;
            cursor[i] = run;
            dinv[i] = rsqrtf((float)(v[k] + 1));  // +1 self-loop
            run += v[k];
        }
    }
}

// ---------------------------------------------------------------------------
// K4: scatter edges into CSR slots; pack {src, weight} as int2.
// ---------------------------------------------------------------------------
__global__ __launch_bounds__(256) void scatter_kernel(
    const int* __restrict__ ei_raw, int nE, const int* __restrict__ flag,
    const float* __restrict__ dinv, int* __restrict__ cursor,
    int2* __restrict__ csr) {
    int e = blockIdx.x * 256 + threadIdx.x;
    if (e >= nE) return;
    int r, c;
    if (*flag) {
        r = ei_raw[e];
        c = ei_raw[nE + e];
    } else {
        const long long* l = (const long long*)ei_raw;
        r = (int)l[e];
        c = (int)l[nE + e];
    }
    int pos = atomicAdd(&cursor[c], 1);
    float w = dinv[r] * dinv[c];
    csr[pos] = make_int2(r, __float_as_int(w));
}

// ---------------------------------------------------------------------------
// K5: h = x @ W1. Tile 64 rows x 128 cols, W1 + x-tile in LDS (96 KB).
// ---------------------------------------------------------------------------
__global__ __launch_bounds__(256) void gemm1_kernel(
    const float* __restrict__ x, const float* __restrict__ W1,
    float* __restrict__ h, int nN) {
    __shared__ float ws[F * F];      // 64 KB
    __shared__ float xs[64 * F];     // 32 KB
    int t = threadIdx.x;
    int row0 = blockIdx.x * 64;

    {
        const float4* w4 = (const float4*)W1;
        float4* ws4 = (float4*)ws;
        for (int i = t; i < F * F / 4; i += 256) ws4[i] = w4[i];
    }
    {
        float4* xs4 = (float4*)xs;
        for (int i = t; i < 64 * F / 4; i += 256) {
            int r = i >> 5;
            int gr = row0 + r;
            float4 v = make_float4(0.f, 0.f, 0.f, 0.f);
            if (gr < nN) v = ((const float4*)x)[(size_t)gr * 32 + (i & 31)];
            xs4[i] = v;
        }
    }
    __syncthreads();

    int ft = t & 31;
    int ng = t >> 5;
    float4 acc[8];
#pragma unroll
    for (int i = 0; i < 8; ++i) acc[i] = make_float4(0.f, 0.f, 0.f, 0.f);

    const float4* wsr = (const float4*)ws;
    for (int k = 0; k < F; ++k) {
        float4 wv = wsr[k * 32 + ft];
#pragma unroll
        for (int i = 0; i < 8; ++i) {
            float xv = xs[(ng * 8 + i) * F + k];
            acc[i].x += xv * wv.x;
            acc[i].y += xv * wv.y;
            acc[i].z += xv * wv.z;
            acc[i].w += xv * wv.w;
        }
    }

#pragma unroll
    for (int i = 0; i < 8; ++i) {
        int gr = row0 + ng * 8 + i;
        if (gr < nN) ((float4*)h)[(size_t)gr * 32 + ft] = acc[i];
    }
}

// ---------------------------------------------------------------------------
// K6: gather-aggregate per node (no atomics):
//   agg[c] = relu(b1 + dinv[c]^2 * h[c] + sum_e w_e * h[src_e])
// 32 lanes per node, 8 nodes per 256-thread block.
// ---------------------------------------------------------------------------
__global__ __launch_bounds__(256) void aggregate_kernel(
    const float* __restrict__ h, const int2* __restrict__ csr,
    const int* __restrict__ off, const int* __restrict__ cnt,
    const float* __restrict__ dinv, const float* __restrict__ b1,
    float* __restrict__ agg, int nN) {
    int t = threadIdx.x;
    int lane = t & 31;
    int c = blockIdx.x * 8 + (t >> 5);
    if (c >= nN) return;

    float di = dinv[c];
    float s = di * di;
    float4 hv = ((const float4*)h)[(size_t)c * 32 + lane];
    float4 bv = ((const float4*)b1)[lane];
    float4 acc;
    acc.x = bv.x + s * hv.x;
    acc.y = bv.y + s * hv.y;
    acc.z = bv.z + s * hv.z;
    acc.w = bv.w + s * hv.w;

    int lo = off[c];
    int n = cnt[c];
    int k = 0;
    for (; k + 1 < n; k += 2) {
        int2 e0 = csr[lo + k];
        int2 e1 = csr[lo + k + 1];
        float4 v0 = ((const float4*)h)[(size_t)e0.x * 32 + lane];
        float4 v1 = ((const float4*)h)[(size_t)e1.x * 32 + lane];
        float w0 = __int_as_float(e0.y);
        float w1 = __int_as_float(e1.y);
        acc.x += w0 * v0.x + w1 * v1.x;
        acc.y += w0 * v0.y + w1 * v1.y;
        acc.z += w0 * v0.z + w1 * v1.z;
        acc.w += w0 * v0.w + w1 * v1.w;
    }
    if (k < n) {
        int2 e0 = csr[lo + k];
        float4 v0 = ((const float4*)h)[(size_t)e0.x * 32 + lane];
        float w0 = __int_as_float(e0.y);
        acc.x += w0 * v0.x;
        acc.y += w0 * v0.y;
        acc.z += w0 * v0.z;
        acc.w += w0 * v0.w;
    }

    float4 r;
    r.x = fmaxf(acc.x, 0.f);
    r.y = fmaxf(acc.y, 0.f);
    r.z = fmaxf(acc.z, 0.f);
    r.w = fmaxf(acc.w, 0.f);
    ((float4*)agg)[(size_t)c * 32 + lane] = r;
}

// ---------------------------------------------------------------------------
// K7: global mean pool (agg already ReLU'd). batch sorted -> binary search.
// ---------------------------------------------------------------------------
__global__ __launch_bounds__(128) void pool_kernel(
    const float* __restrict__ agg, const int* __restrict__ batch32,
    float* __restrict__ pooled, int nN) {
    int g = blockIdx.x;
    __shared__ int bounds[2];
    if (threadIdx.x < 2) {
        int target = g + threadIdx.x;
        int lo = 0, hi = nN;
        while (lo < hi) {
            int mid = (lo + hi) >> 1;
            if (batch32[mid] < target) lo = mid + 1; else hi = mid;
        }
        bounds[threadIdx.x] = lo;
    }
    __syncthreads();
    int lo = bounds[0], hi = bounds[1];
    int j = threadIdx.x;
    float acc = 0.f;
    for (int n = lo; n < hi; ++n) acc += agg[(size_t)n * F + j];
    float cnt = (float)(hi - lo);
    pooled[g * F + j] = acc / fmaxf(cnt, 1.0f);
}

// ---------------------------------------------------------------------------
// K8: out = tanh(pooled @ W2 + b2).
// ---------------------------------------------------------------------------
__global__ __launch_bounds__(128) void final_kernel(
    const float* __restrict__ pooled, const float* __restrict__ W2,
    const float* __restrict__ b2, float* __restrict__ out) {
    int g = blockIdx.x;
    __shared__ float ps[F];
    ps[threadIdx.x] = pooled[g * F + threadIdx.x];
    __syncthreads();
    int j = threadIdx.x;
    float s = b2[j];
    for (int k = 0; k < F; ++k) s += ps[k] * W2[k * F + j];
    out[g * F + j] = tanhf(s);
}

// ---------------------------------------------------------------------------
extern "C" void kernel_launch(void* const* d_in, const int* in_sizes, int n_in,
                              void* d_out, int out_size, void* d_ws, size_t ws_size,
                              hipStream_t stream) {
    const float* x     = (const float*)d_in[0];
    const int*   ei    = (const int*)d_in[1];   // [2][E], dtype sniffed on device
    const int*   batch = (const int*)d_in[2];
    const float* W1    = (const float*)d_in[3];
    const float* b1    = (const float*)d_in[4];
    const float* W2    = (const float*)d_in[5];
    const float* b2    = (const float*)d_in[6];
    float* out = (float*)d_out;

    const int nN = in_sizes[2];          // 100000
    const int nE = in_sizes[1] / 2;      // 1600000
    const int nB = (nN + 1023) / 1024;   // scan blocks (98 <= 256)

    // workspace layout (16B-aligned slabs)
    char* ws = (char*)d_ws;
    size_t woff = 0;
    auto take = [&](size_t bytes) {
        void* p = ws + woff;
        woff += (bytes + 15) & ~(size_t)15;
        return p;
    };
    float* h        = (float*)take((size_t)nN * F * 4);
    float* agg      = (float*)take((size_t)nN * F * 4);
    int2*  csr      = (int2*)take((size_t)nE * 8);
    int*   cnt      = (int*)take((size_t)nN * 4);
    int*   off      = (int*)take((size_t)nN * 4);
    int*   cursor   = (int*)take((size_t)nN * 4);
    float* dinv     = (float*)take((size_t)nN * 4);
    int*   batch32  = (int*)take((size_t)nN * 4);
    float* pooled   = (float*)take((size_t)N_GRAPHS * F * 4);
    int*   blockSum = (int*)take((size_t)nB * 4);
    int*   flag     = (int*)take(4);

    detect_kernel<<<1, 64, 0, stream>>>(batch, nN, flag);
    prep_kernel<<<(nN + 255) / 256, 256, 0, stream>>>(batch, nN, flag, batch32, cnt);
    count_kernel<<<(nE + 255) / 256, 256, 0, stream>>>(ei, nE, flag, cnt);
    scanA_kernel<<<nB, 256, 0, stream>>>(cnt, nN, blockSum);
    scanB_kernel<<<1, 256, 0, stream>>>(blockSum, nB);
    scanC_kernel<<<nB, 256, 0, stream>>>(cnt, nN, blockSum, off, cursor, dinv);
    scatter_kernel<<<(nE + 255) / 256, 256, 0, stream>>>(ei, nE, flag, dinv, cursor, csr);
    gemm1_kernel<<<(nN + 63) / 64, 256, 0, stream>>>(x, W1, h, nN);
    aggregate_kernel<<<(nN + 7) / 8, 256, 0, stream>>>(h, csr, off, cnt, dinv, b1, agg, nN);
    pool_kernel<<<N_GRAPHS, 128, 0, stream>>>(agg, batch32, pooled, nN);
    final_kernel<<<N_GRAPHS, 128, 0, stream>>>(pooled, W2, b2, out);
}

// Round 3
// 305.604 us; speedup vs baseline: 9.7881x; 1.6100x over previous
//
#include <hip/hip_runtime.h>
#include <math.h>

#define F 128   // F_IN == F_HID == F_OUT == 128
#define N_GRAPHS 256

// ---- bf16 helpers (storage only; all math in f32) --------------------------
__device__ __forceinline__ unsigned short f2bf(float f) {
    unsigned u = __float_as_uint(f);
    unsigned r = (u + 0x7FFFu + ((u >> 16) & 1u)) >> 16;  // round-nearest-even
    return (unsigned short)r;
}
__device__ __forceinline__ float bf2f(unsigned short u) {
    return __uint_as_float(((unsigned)u) << 16);
}
// dtype-aware index read: int64 inputs have zero high words (values < 2^31)
__device__ __forceinline__ int idxval(const int* raw, int i, bool is32) {
    return is32 ? raw[i] : (int)((const long long*)raw)[i];
}

// ---------------------------------------------------------------------------
// K1: in-degree counts (int atomics, 400KB L2-resident array).
// ---------------------------------------------------------------------------
__global__ __launch_bounds__(256) void count_kernel(
    const int* __restrict__ ei_raw, int nE,
    const int* __restrict__ batch_raw, int nN, int* __restrict__ cnt) {
    bool is32 = (batch_raw[nN - 1] != 0);
    int e = blockIdx.x * 256 + threadIdx.x;
    if (e >= nE) return;
    int c = idxval(ei_raw, nE + e, is32);
    atomicAdd(&cnt[c], 1);
}

// ---------------------------------------------------------------------------
// K2a/b/c: exclusive scan of cnt -> off (3-pass), chunk = 1024 per block.
// scanC also derives cursor (= off copy) and dinv = rsqrt(deg+1).
// ---------------------------------------------------------------------------
__global__ __launch_bounds__(256) void scanA_kernel(
    const int* __restrict__ cnt, int nN, int* __restrict__ blockSum) {
    __shared__ int sd[256];
    int base = blockIdx.x * 1024;
    int t = threadIdx.x;
    int s = 0;
#pragma unroll
    for (int k = 0; k < 4; ++k) {
        int i = base + t * 4 + k;
        if (i < nN) s += cnt[i];
    }
    sd[t] = s;
    __syncthreads();
    for (int st = 128; st > 0; st >>= 1) {
        if (t < st) sd[t] += sd[t + st];
        __syncthreads();
    }
    if (t == 0) blockSum[blockIdx.x] = sd[0];
}

__global__ __launch_bounds__(256) void scanB_kernel(int* __restrict__ blockSum,
                                                    int nB) {
    __shared__ int sd[256];
    int t = threadIdx.x;
    int v = (t < nB) ? blockSum[t] : 0;
    sd[t] = v;
    __syncthreads();
    for (int st = 1; st < 256; st <<= 1) {
        int add = (t >= st) ? sd[t - st] : 0;
        __syncthreads();
        sd[t] += add;
        __syncthreads();
    }
    if (t < nB) blockSum[t] = sd[t] - v;  // exclusive
}

__global__ __launch_bounds__(256) void scanC_kernel(
    const int* __restrict__ cnt, int nN, const int* __restrict__ blockOff,
    int* __restrict__ off, int* __restrict__ cursor, float* __restrict__ dinv) {
    __shared__ int sd[256];
    int base = blockIdx.x * 1024;
    int t = threadIdx.x;
    int v[4];
    int s = 0;
#pragma unroll
    for (int k = 0; k < 4; ++k) {
        int i = base + t * 4 + k;
        v[k] = (i < nN) ? cnt[i] : 0;
        s += v[k];
    }
    sd[t] = s;
    __syncthreads();
    for (int st = 1; st < 256; st <<= 1) {
        int add = (t >= st) ? sd[t - st] : 0;
        __syncthreads();
        sd[t] += add;
        __syncthreads();
    }
    int run = blockOff[blockIdx.x] + sd[t] - s;  // exclusive prefix
#pragma unroll
    for (int k = 0; k < 4; ++k) {
        int i = base + t * 4 + k;
        if (i < nN) {
            off[i] = run;
            cursor[i] = run;
            dinv[i] = rsqrtf((float)(v[k] + 1));  // +1 self-loop
            run += v[k];
        }
    }
}

// ---------------------------------------------------------------------------
// K3: scatter edges into CSR slots; pack {src, weight} as int2.
// ---------------------------------------------------------------------------
__global__ __launch_bounds__(256) void scatter_kernel(
    const int* __restrict__ ei_raw, int nE,
    const int* __restrict__ batch_raw, int nN,
    const float* __restrict__ dinv, int* __restrict__ cursor,
    int2* __restrict__ csr) {
    bool is32 = (batch_raw[nN - 1] != 0);
    int e = blockIdx.x * 256 + threadIdx.x;
    if (e >= nE) return;
    int r = idxval(ei_raw, e, is32);
    int c = idxval(ei_raw, nE + e, is32);
    int pos = atomicAdd(&cursor[c], 1);
    float w = dinv[r] * dinv[c];
    csr[pos] = make_int2(r, __float_as_int(w));
}

// ---------------------------------------------------------------------------
// K4: h = x @ W1, stored as bf16. Tile 32 rows x 128 cols; LDS = 80 KB
// (W1 64 KB + x-tile 16 KB) -> 2 blocks/CU. 256 thr: 8 row-groups x 32
// feature-threads; thread owns 4 rows x float4. k-loop in chunks of 4 so
// both LDS operands use b128 reads.
// ---------------------------------------------------------------------------
__global__ __launch_bounds__(256) void gemm1_kernel(
    const float* __restrict__ x, const float* __restrict__ W1,
    unsigned short* __restrict__ h_bf, int nN) {
    __shared__ float ws[F * F];      // 64 KB
    __shared__ float xs[32 * F];     // 16 KB
    int t = threadIdx.x;
    int row0 = blockIdx.x * 32;

    {
        const float4* w4 = (const float4*)W1;
        float4* ws4 = (float4*)ws;
        for (int i = t; i < F * F / 4; i += 256) ws4[i] = w4[i];
    }
    {
        float4* xs4 = (float4*)xs;
        for (int i = t; i < 32 * F / 4; i += 256) {
            int r = i >> 5;
            int gr = row0 + r;
            float4 v = make_float4(0.f, 0.f, 0.f, 0.f);
            if (gr < nN) v = ((const float4*)x)[(size_t)gr * 32 + (i & 31)];
            xs4[i] = v;
        }
    }
    __syncthreads();

    int ft = t & 31;   // feature float4 index
    int ng = t >> 5;   // row group: rows ng*4 .. ng*4+3
    float4 acc[4];
#pragma unroll
    for (int i = 0; i < 4; ++i) acc[i] = make_float4(0.f, 0.f, 0.f, 0.f);

    const float4* ws4 = (const float4*)ws;
    const float4* xs4 = (const float4*)xs;
    for (int k4 = 0; k4 < 32; ++k4) {
        float4 wv0 = ws4[(k4 * 4 + 0) * 32 + ft];
        float4 wv1 = ws4[(k4 * 4 + 1) * 32 + ft];
        float4 wv2 = ws4[(k4 * 4 + 2) * 32 + ft];
        float4 wv3 = ws4[(k4 * 4 + 3) * 32 + ft];
#pragma unroll
        for (int i = 0; i < 4; ++i) {
            float4 xv = xs4[(ng * 4 + i) * 32 + k4];
            acc[i].x += xv.x * wv0.x + xv.y * wv1.x + xv.z * wv2.x + xv.w * wv3.x;
            acc[i].y += xv.x * wv0.y + xv.y * wv1.y + xv.z * wv2.y + xv.w * wv3.y;
            acc[i].z += xv.x * wv0.z + xv.y * wv1.z + xv.z * wv2.z + xv.w * wv3.z;
            acc[i].w += xv.x * wv0.w + xv.y * wv1.w + xv.z * wv2.w + xv.w * wv3.w;
        }
    }

#pragma unroll
    for (int i = 0; i < 4; ++i) {
        int gr = row0 + ng * 4 + i;
        if (gr < nN) {
            ushort4 o;
            o.x = f2bf(acc[i].x);
            o.y = f2bf(acc[i].y);
            o.z = f2bf(acc[i].z);
            o.w = f2bf(acc[i].w);
            ((ushort4*)h_bf)[(size_t)gr * 32 + ft] = o;
        }
    }
}

// ---------------------------------------------------------------------------
// K5: gather-aggregate per node (no atomics), bf16 h in / bf16 agg out:
//   agg[c] = relu(b1 + dinv[c]^2 * h[c] + sum_e w_e * h[src_e])
// 32 lanes per node (ushort4 = 4 features each), 8 nodes / 256-thr block.
// Edge loop unrolled x4 for MLP.
// ---------------------------------------------------------------------------
__global__ __launch_bounds__(256) void aggregate_kernel(
    const unsigned short* __restrict__ h_bf, const int2* __restrict__ csr,
    const int* __restrict__ off, const int* __restrict__ cnt,
    const float* __restrict__ dinv, const float* __restrict__ b1,
    unsigned short* __restrict__ agg_bf, int nN) {
    int t = threadIdx.x;
    int lane = t & 31;
    int c = blockIdx.x * 8 + (t >> 5);
    if (c >= nN) return;

    const ushort4* h4 = (const ushort4*)h_bf;
    float di = dinv[c];
    float s = di * di;
    ushort4 hv = h4[(size_t)c * 32 + lane];
    float4 bv = ((const float4*)b1)[lane];
    float4 acc;
    acc.x = bv.x + s * bf2f(hv.x);
    acc.y = bv.y + s * bf2f(hv.y);
    acc.z = bv.z + s * bf2f(hv.z);
    acc.w = bv.w + s * bf2f(hv.w);

    int lo = off[c];
    int n = cnt[c];
    int k = 0;
    for (; k + 3 < n; k += 4) {
        int2 e0 = csr[lo + k];
        int2 e1 = csr[lo + k + 1];
        int2 e2 = csr[lo + k + 2];
        int2 e3 = csr[lo + k + 3];
        ushort4 v0 = h4[(size_t)e0.x * 32 + lane];
        ushort4 v1 = h4[(size_t)e1.x * 32 + lane];
        ushort4 v2 = h4[(size_t)e2.x * 32 + lane];
        ushort4 v3 = h4[(size_t)e3.x * 32 + lane];
        float w0 = __int_as_float(e0.y);
        float w1 = __int_as_float(e1.y);
        float w2 = __int_as_float(e2.y);
        float w3 = __int_as_float(e3.y);
        acc.x += w0 * bf2f(v0.x) + w1 * bf2f(v1.x) + w2 * bf2f(v2.x) + w3 * bf2f(v3.x);
        acc.y += w0 * bf2f(v0.y) + w1 * bf2f(v1.y) + w2 * bf2f(v2.y) + w3 * bf2f(v3.y);
        acc.z += w0 * bf2f(v0.z) + w1 * bf2f(v1.z) + w2 * bf2f(v2.z) + w3 * bf2f(v3.z);
        acc.w += w0 * bf2f(v0.w) + w1 * bf2f(v1.w) + w2 * bf2f(v2.w) + w3 * bf2f(v3.w);
    }
    for (; k < n; ++k) {
        int2 e0 = csr[lo + k];
        ushort4 v0 = h4[(size_t)e0.x * 32 + lane];
        float w0 = __int_as_float(e0.y);
        acc.x += w0 * bf2f(v0.x);
        acc.y += w0 * bf2f(v0.y);
        acc.z += w0 * bf2f(v0.z);
        acc.w += w0 * bf2f(v0.w);
    }

    ushort4 r;
    r.x = f2bf(fmaxf(acc.x, 0.f));
    r.y = f2bf(fmaxf(acc.y, 0.f));
    r.z = f2bf(fmaxf(acc.z, 0.f));
    r.w = f2bf(fmaxf(acc.w, 0.f));
    ((ushort4*)agg_bf)[(size_t)c * 32 + lane] = r;
}

// ---------------------------------------------------------------------------
// K6: fused global-mean-pool + linear + tanh. One block per graph, 256 thr.
// Phase 1: 8 node-groups x 32 lanes accumulate float4 columns; LDS reduce.
// Phase 2: first 128 threads do pooled @ W2 + b2, tanh, store.
// ---------------------------------------------------------------------------
__global__ __launch_bounds__(256) void pool_final_kernel(
    const unsigned short* __restrict__ agg_bf,
    const int* __restrict__ batch_raw, int nN,
    const float* __restrict__ W2, const float* __restrict__ b2,
    float* __restrict__ out) {
    int g = blockIdx.x;
    bool is32 = (batch_raw[nN - 1] != 0);
    __shared__ int bounds[2];
    __shared__ float sd[8][F];
    __shared__ float ps[F];
    int t = threadIdx.x;
    if (t < 2) {
        int target = g + t;
        int lo = 0, hi = nN;
        while (lo < hi) {
            int mid = (lo + hi) >> 1;
            if (idxval(batch_raw, mid, is32) < target) lo = mid + 1; else hi = mid;
        }
        bounds[t] = lo;
    }
    __syncthreads();
    int lo = bounds[0], hi = bounds[1];

    int lane = t & 31;
    int grp = t >> 5;
    const ushort4* a4 = (const ushort4*)agg_bf;
    float4 acc = make_float4(0.f, 0.f, 0.f, 0.f);
    for (int n = lo + grp; n < hi; n += 8) {
        ushort4 v = a4[(size_t)n * 32 + lane];
        acc.x += bf2f(v.x);
        acc.y += bf2f(v.y);
        acc.z += bf2f(v.z);
        acc.w += bf2f(v.w);
    }
    sd[grp][lane * 4 + 0] = acc.x;
    sd[grp][lane * 4 + 1] = acc.y;
    sd[grp][lane * 4 + 2] = acc.z;
    sd[grp][lane * 4 + 3] = acc.w;
    __syncthreads();

    if (t < F) {
        float s = 0.f;
#pragma unroll
        for (int i = 0; i < 8; ++i) s += sd[i][t];
        float cntf = (float)(hi - lo);
        ps[t] = s / fmaxf(cntf, 1.0f);
    }
    __syncthreads();

    if (t < F) {
        float s = b2[t];
        for (int k = 0; k < F; ++k) s += ps[k] * W2[k * F + t];
        out[g * F + t] = tanhf(s);
    }
}

// ---------------------------------------------------------------------------
extern "C" void kernel_launch(void* const* d_in, const int* in_sizes, int n_in,
                              void* d_out, int out_size, void* d_ws, size_t ws_size,
                              hipStream_t stream) {
    const float* x     = (const float*)d_in[0];
    const int*   ei    = (const int*)d_in[1];   // [2][E], dtype sniffed on device
    const int*   batch = (const int*)d_in[2];
    const float* W1    = (const float*)d_in[3];
    const float* b1    = (const float*)d_in[4];
    const float* W2    = (const float*)d_in[5];
    const float* b2    = (const float*)d_in[6];
    float* out = (float*)d_out;

    const int nN = in_sizes[2];          // 100000
    const int nE = in_sizes[1] / 2;      // 1600000
    const int nB = (nN + 1023) / 1024;   // scan blocks (98 <= 256)

    // workspace layout (16B-aligned slabs)
    char* ws = (char*)d_ws;
    size_t woff = 0;
    auto take = [&](size_t bytes) {
        void* p = ws + woff;
        woff += (bytes + 15) & ~(size_t)15;
        return p;
    };
    unsigned short* h_bf   = (unsigned short*)take((size_t)nN * F * 2);
    unsigned short* agg_bf = (unsigned short*)take((size_t)nN * F * 2);
    int2*  csr      = (int2*)take((size_t)nE * 8);
    int*   cnt      = (int*)take((size_t)nN * 4);
    int*   off      = (int*)take((size_t)nN * 4);
    int*   cursor   = (int*)take((size_t)nN * 4);
    float* dinv     = (float*)take((size_t)nN * 4);
    int*   blockSum = (int*)take((size_t)nB * 4);

    hipMemsetAsync(cnt, 0, (size_t)nN * 4, stream);
    count_kernel<<<(nE + 255) / 256, 256, 0, stream>>>(ei, nE, batch, nN, cnt);
    scanA_kernel<<<nB, 256, 0, stream>>>(cnt, nN, blockSum);
    scanB_kernel<<<1, 256, 0, stream>>>(blockSum, nB);
    scanC_kernel<<<nB, 256, 0, stream>>>(cnt, nN, blockSum, off, cursor, dinv);
    scatter_kernel<<<(nE + 255) / 256, 256, 0, stream>>>(ei, nE, batch, nN, dinv, cursor, csr);
    gemm1_kernel<<<(nN + 31) / 32, 256, 0, stream>>>(x, W1, h_bf, nN);
    aggregate_kernel<<<(nN + 7) / 8, 256, 0, stream>>>(h_bf, csr, off, cnt, dinv, b1, agg_bf, nN);
    pool_final_kernel<<<N_GRAPHS, 256, 0, stream>>>(agg_bf, batch, nN, W2, b2, out);
}

// Round 4
// 273.568 us; speedup vs baseline: 10.9343x; 1.1171x over previous
//
#include <hip/hip_runtime.h>
#include <math.h>

#define F 128   // F_IN == F_HID == F_OUT == 128
#define N_GRAPHS 256

typedef __attribute__((ext_vector_type(4))) float f32x4;
typedef __attribute__((ext_vector_type(8))) short bf16x8;

// ---- bf16 helpers (storage only; math in f32) ------------------------------
__device__ __forceinline__ unsigned short f2bf(float f) {
    unsigned u = __float_as_uint(f);
    unsigned r = (u + 0x7FFFu + ((u >> 16) & 1u)) >> 16;  // round-nearest-even
    return (unsigned short)r;
}
__device__ __forceinline__ float bf2f(unsigned short u) {
    return __uint_as_float(((unsigned)u) << 16);
}
// dtype-aware index read: int64 inputs have zero high words (values < 2^31)
__device__ __forceinline__ int idxval(const int* raw, int i, bool is32) {
    return is32 ? raw[i] : (int)((const long long*)raw)[i];
}

// ---------------------------------------------------------------------------
// K0: W1 (f32 [k][n]) -> W1T (bf16 [n][k]). 16K elems, one-shot.
// ---------------------------------------------------------------------------
__global__ __launch_bounds__(256) void w1t_kernel(
    const float* __restrict__ W1, unsigned short* __restrict__ W1T) {
    int i = blockIdx.x * 256 + threadIdx.x;   // 16384
    int k = i >> 7, n = i & 127;
    W1T[n * F + k] = f2bf(W1[i]);
}

// ---------------------------------------------------------------------------
// K1: convert edge_index -> int32 row32/col32 (dtype sniffed via batch).
// ---------------------------------------------------------------------------
__global__ __launch_bounds__(256) void convert_kernel(
    const int* __restrict__ ei_raw, int nE,
    const int* __restrict__ batch_raw, int nN,
    int* __restrict__ row32, int* __restrict__ col32) {
    bool is32 = (batch_raw[nN - 1] != 0);
    int e = blockIdx.x * 256 + threadIdx.x;
    if (e >= nE) return;
    row32[e] = idxval(ei_raw, e, is32);
    col32[e] = idxval(ei_raw, nE + e, is32);
}

// ---------------------------------------------------------------------------
// K2: XCD-sliced in-degree count. Block b: dest slice b&7 (== its XCD under
// round-robin dispatch), edge chunk b>>3. Atomics stay XCD-L2-local.
// ---------------------------------------------------------------------------
__global__ __launch_bounds__(256) void count_sliced_kernel(
    const int* __restrict__ col32, int nE, int nN, int* __restrict__ cnt) {
    int s = blockIdx.x & 7;
    int cb = blockIdx.x >> 3;                 // 0..255
    int cs = (nE + 255) / 256;
    int lo = (int)(((long long)nN * s) >> 3);
    int hi = (int)(((long long)nN * (s + 1)) >> 3);
    int end = min(nE, (cb + 1) * cs);
    for (int e = cb * cs + threadIdx.x; e < end; e += 256) {
        int c = col32[e];
        if (c >= lo && c < hi) atomicAdd(&cnt[c], 1);
    }
}

// ---------------------------------------------------------------------------
// K3a/b/c: exclusive scan of cnt -> off/cursor; dinv = rsqrt(deg+1).
// ---------------------------------------------------------------------------
__global__ __launch_bounds__(256) void scanA_kernel(
    const int* __restrict__ cnt, int nN, int* __restrict__ blockSum) {
    __shared__ int sd[256];
    int base = blockIdx.x * 1024;
    int t = threadIdx.x;
    int s = 0;
#pragma unroll
    for (int k = 0; k < 4; ++k) {
        int i = base + t * 4 + k;
        if (i < nN) s += cnt[i];
    }
    sd[t] = s;
    __syncthreads();
    for (int st = 128; st > 0; st >>= 1) {
        if (t < st) sd[t] += sd[t + st];
        __syncthreads();
    }
    if (t == 0) blockSum[blockIdx.x] = sd[0];
}

__global__ __launch_bounds__(256) void scanB_kernel(int* __restrict__ blockSum,
                                                    int nB) {
    __shared__ int sd[256];
    int t = threadIdx.x;
    int v = (t < nB) ? blockSum[t] : 0;
    sd[t] = v;
    __syncthreads();
    for (int st = 1; st < 256; st <<= 1) {
        int add = (t >= st) ? sd[t - st] : 0;
        __syncthreads();
        sd[t] += add;
        __syncthreads();
    }
    if (t < nB) blockSum[t] = sd[t] - v;  // exclusive
}

__global__ __launch_bounds__(256) void scanC_kernel(
    const int* __restrict__ cnt, int nN, const int* __restrict__ blockOff,
    int* __restrict__ off, int* __restrict__ cursor, float* __restrict__ dinv) {
    __shared__ int sd[256];
    int base = blockIdx.x * 1024;
    int t = threadIdx.x;
    int v[4];
    int s = 0;
#pragma unroll
    for (int k = 0; k < 4; ++k) {
        int i = base + t * 4 + k;
        v[k] = (i < nN) ? cnt[i] : 0;
        s += v[k];
    }
    sd[t] = s;
    __syncthreads();
    for (int st = 1; st < 256; st <<= 1) {
        int add = (t >= st) ? sd[t - st] : 0;
        __syncthreads();
        sd[t] += add;
        __syncthreads();
    }
    int run = blockOff[blockIdx.x] + sd[t] - s;  // exclusive prefix
#pragma unroll
    for (int k = 0; k < 4; ++k) {
        int i = base + t * 4 + k;
        if (i < nN) {
            off[i] = run;
            cursor[i] = run;
            dinv[i] = rsqrtf((float)(v[k] + 1));  // +1 self-loop
            run += v[k];
        }
    }
}

// ---------------------------------------------------------------------------
// K4: XCD-sliced CSR scatter. Same slicing as K2: each XCD writes only its
// contiguous 1/8 of csr (fits 4MB L2 -> line writes merge), cursor atomics
// XCD-local. Payload {src, w=dinv[r]*dinv[c]} as int2.
// ---------------------------------------------------------------------------
__global__ __launch_bounds__(256) void scatter_sliced_kernel(
    const int* __restrict__ row32, const int* __restrict__ col32, int nE,
    int nN, const float* __restrict__ dinv, int* __restrict__ cursor,
    int2* __restrict__ csr) {
    int s = blockIdx.x & 7;
    int cb = blockIdx.x >> 3;
    int cs = (nE + 255) / 256;
    int lo = (int)(((long long)nN * s) >> 3);
    int hi = (int)(((long long)nN * (s + 1)) >> 3);
    int end = min(nE, (cb + 1) * cs);
    for (int e = cb * cs + threadIdx.x; e < end; e += 256) {
        int c = col32[e];
        if (c >= lo && c < hi) {
            int r = row32[e];
            float w = dinv[r] * dinv[c];
            int pos = atomicAdd(&cursor[c], 1);
            csr[pos] = make_int2(r, __float_as_int(w));
        }
    }
}

// ---------------------------------------------------------------------------
// K5: h = x @ W1 via MFMA bf16. 128x128 tile/block, 4 waves (2x2 of 64x64).
// x staged f32->bf16 into XOR-swizzled LDS; W1T b-frags straight from L2.
// A-frag: lane l -> A[m0+i*16 + (l&15)][ks*32 + (l>>4)*8 + 0..7]
// B-frag: lane l -> W1T[n0+j*16 + (l&15)][ks*32 + (l>>4)*8 + 0..7]
// D frag: row = (l>>4)*4 + reg, col = l&15   [m89-verified layout]
// ---------------------------------------------------------------------------
__global__ __launch_bounds__(256) void gemm1_mfma_kernel(
    const float* __restrict__ x, const unsigned short* __restrict__ W1T,
    unsigned short* __restrict__ h_bf, int nN) {
    __shared__ unsigned short xs[128 * F];   // 32 KB bf16, swizzled
    int t = threadIdx.x;
    int row0 = blockIdx.x * 128;

    // stage x tile -> bf16 LDS (zero-pad past nN)
#pragma unroll
    for (int j = 0; j < 16; ++j) {
        int idx = t + j * 256;        // float4 index within [128][32]
        int r = idx >> 5, c4 = idx & 31;
        int gr = row0 + r;
        float4 v = make_float4(0.f, 0.f, 0.f, 0.f);
        if (gr < nN) v = ((const float4*)x)[(size_t)gr * 32 + c4];
        ushort4 o;
        o.x = f2bf(v.x); o.y = f2bf(v.y); o.z = f2bf(v.z); o.w = f2bf(v.w);
        int byte = (r * 256 + c4 * 8) ^ ((r & 7) << 4);
        *(ushort4*)((char*)xs + byte) = o;
    }
    __syncthreads();

    int lane = t & 63;
    int w = t >> 6;              // wave 0..3
    int m0 = (w >> 1) * 64;      // block-local row base
    int n0 = (w & 1) * 64;       // col base
    int l15 = lane & 15;
    int lg = lane >> 4;          // 0..3

    f32x4 acc[4][4] = {};
#pragma unroll
    for (int ks = 0; ks < 4; ++ks) {
        bf16x8 a[4], b[4];
#pragma unroll
        for (int i = 0; i < 4; ++i) {
            int r = m0 + i * 16 + l15;
            int byte = (r * 256 + ks * 64 + lg * 16) ^ ((r & 7) << 4);
            a[i] = *(const bf16x8*)((const char*)xs + byte);
        }
#pragma unroll
        for (int j = 0; j < 4; ++j) {
            int n = n0 + j * 16 + l15;
            b[j] = *(const bf16x8*)(W1T + (size_t)n * F + ks * 32 + lg * 8);
        }
#pragma unroll
        for (int i = 0; i < 4; ++i)
#pragma unroll
            for (int j = 0; j < 4; ++j)
                acc[i][j] = __builtin_amdgcn_mfma_f32_16x16x32_bf16(
                    a[i], b[j], acc[i][j], 0, 0, 0);
    }

    // epilogue: bf16 store, row-guarded
#pragma unroll
    for (int i = 0; i < 4; ++i) {
#pragma unroll
        for (int r = 0; r < 4; ++r) {
            int gm = row0 + m0 + i * 16 + lg * 4 + r;
            if (gm < nN) {
#pragma unroll
                for (int j = 0; j < 4; ++j) {
                    int n = n0 + j * 16 + l15;
                    h_bf[(size_t)gm * F + n] = f2bf(acc[i][j][r]);
                }
            }
        }
    }
}

// ---------------------------------------------------------------------------
// K6: gather-aggregate per node (no atomics), bf16 in/out:
//   agg[c] = relu(b1 + dinv[c]^2 * h[c] + sum_e w_e * h[src_e])
// 32 lanes per node (ushort4 each), 8 nodes / 256-thr block, unroll x4.
// ---------------------------------------------------------------------------
__global__ __launch_bounds__(256) void aggregate_kernel(
    const unsigned short* __restrict__ h_bf, const int2* __restrict__ csr,
    const int* __restrict__ off, const int* __restrict__ cnt,
    const float* __restrict__ dinv, const float* __restrict__ b1,
    unsigned short* __restrict__ agg_bf, int nN) {
    int t = threadIdx.x;
    int lane = t & 31;
    int c = blockIdx.x * 8 + (t >> 5);
    if (c >= nN) return;

    const ushort4* h4 = (const ushort4*)h_bf;
    float di = dinv[c];
    float s = di * di;
    ushort4 hv = h4[(size_t)c * 32 + lane];
    float4 bv = ((const float4*)b1)[lane];
    float4 acc;
    acc.x = bv.x + s * bf2f(hv.x);
    acc.y = bv.y + s * bf2f(hv.y);
    acc.z = bv.z + s * bf2f(hv.z);
    acc.w = bv.w + s * bf2f(hv.w);

    int lo = off[c];
    int n = cnt[c];
    int k = 0;
    for (; k + 3 < n; k += 4) {
        int2 e0 = csr[lo + k];
        int2 e1 = csr[lo + k + 1];
        int2 e2 = csr[lo + k + 2];
        int2 e3 = csr[lo + k + 3];
        ushort4 v0 = h4[(size_t)e0.x * 32 + lane];
        ushort4 v1 = h4[(size_t)e1.x * 32 + lane];
        ushort4 v2 = h4[(size_t)e2.x * 32 + lane];
        ushort4 v3 = h4[(size_t)e3.x * 32 + lane];
        float w0 = __int_as_float(e0.y);
        float w1 = __int_as_float(e1.y);
        float w2 = __int_as_float(e2.y);
        float w3 = __int_as_float(e3.y);
        acc.x += w0 * bf2f(v0.x) + w1 * bf2f(v1.x) + w2 * bf2f(v2.x) + w3 * bf2f(v3.x);
        acc.y += w0 * bf2f(v0.y) + w1 * bf2f(v1.y) + w2 * bf2f(v2.y) + w3 * bf2f(v3.y);
        acc.z += w0 * bf2f(v0.z) + w1 * bf2f(v1.z) + w2 * bf2f(v2.z) + w3 * bf2f(v3.z);
        acc.w += w0 * bf2f(v0.w) + w1 * bf2f(v1.w) + w2 * bf2f(v2.w) + w3 * bf2f(v3.w);
    }
    for (; k < n; ++k) {
        int2 e0 = csr[lo + k];
        ushort4 v0 = h4[(size_t)e0.x * 32 + lane];
        float w0 = __int_as_float(e0.y);
        acc.x += w0 * bf2f(v0.x);
        acc.y += w0 * bf2f(v0.y);
        acc.z += w0 * bf2f(v0.z);
        acc.w += w0 * bf2f(v0.w);
    }

    ushort4 r;
    r.x = f2bf(fmaxf(acc.x, 0.f));
    r.y = f2bf(fmaxf(acc.y, 0.f));
    r.z = f2bf(fmaxf(acc.z, 0.f));
    r.w = f2bf(fmaxf(acc.w, 0.f));
    ((ushort4*)agg_bf)[(size_t)c * 32 + lane] = r;
}

// ---------------------------------------------------------------------------
// K7: fused global-mean-pool + linear + tanh. One block per graph, 256 thr.
// ---------------------------------------------------------------------------
__global__ __launch_bounds__(256) void pool_final_kernel(
    const unsigned short* __restrict__ agg_bf,
    const int* __restrict__ batch_raw, int nN,
    const float* __restrict__ W2, const float* __restrict__ b2,
    float* __restrict__ out) {
    int g = blockIdx.x;
    bool is32 = (batch_raw[nN - 1] != 0);
    __shared__ int bounds[2];
    __shared__ float sd[8][F];
    __shared__ float ps[F];
    int t = threadIdx.x;
    if (t < 2) {
        int target = g + t;
        int lo = 0, hi = nN;
        while (lo < hi) {
            int mid = (lo + hi) >> 1;
            if (idxval(batch_raw, mid, is32) < target) lo = mid + 1; else hi = mid;
        }
        bounds[t] = lo;
    }
    __syncthreads();
    int lo = bounds[0], hi = bounds[1];

    int lane = t & 31;
    int grp = t >> 5;
    const ushort4* a4 = (const ushort4*)agg_bf;
    float4 acc = make_float4(0.f, 0.f, 0.f, 0.f);
    for (int n = lo + grp; n < hi; n += 8) {
        ushort4 v = a4[(size_t)n * 32 + lane];
        acc.x += bf2f(v.x);
        acc.y += bf2f(v.y);
        acc.z += bf2f(v.z);
        acc.w += bf2f(v.w);
    }
    sd[grp][lane * 4 + 0] = acc.x;
    sd[grp][lane * 4 + 1] = acc.y;
    sd[grp][lane * 4 + 2] = acc.z;
    sd[grp][lane * 4 + 3] = acc.w;
    __syncthreads();

    if (t < F) {
        float s = 0.f;
#pragma unroll
        for (int i = 0; i < 8; ++i) s += sd[i][t];
        float cntf = (float)(hi - lo);
        ps[t] = s / fmaxf(cntf, 1.0f);
    }
    __syncthreads();

    if (t < F) {
        float s = b2[t];
        for (int k = 0; k < F; ++k) s += ps[k] * W2[k * F + t];
        out[g * F + t] = tanhf(s);
    }
}

// ---------------------------------------------------------------------------
extern "C" void kernel_launch(void* const* d_in, const int* in_sizes, int n_in,
                              void* d_out, int out_size, void* d_ws, size_t ws_size,
                              hipStream_t stream) {
    const float* x     = (const float*)d_in[0];
    const int*   ei    = (const int*)d_in[1];
    const int*   batch = (const int*)d_in[2];
    const float* W1    = (const float*)d_in[3];
    const float* b1    = (const float*)d_in[4];
    const float* W2    = (const float*)d_in[5];
    const float* b2    = (const float*)d_in[6];
    float* out = (float*)d_out;

    const int nN = in_sizes[2];          // 100000
    const int nE = in_sizes[1] / 2;      // 1600000
    const int nB = (nN + 1023) / 1024;   // scan blocks (98 <= 256)

    char* ws = (char*)d_ws;
    size_t woff = 0;
    auto take = [&](size_t bytes) {
        void* p = ws + woff;
        woff += (bytes + 15) & ~(size_t)15;
        return p;
    };
    unsigned short* h_bf   = (unsigned short*)take((size_t)nN * F * 2);
    unsigned short* agg_bf = (unsigned short*)take((size_t)nN * F * 2);
    int2*  csr      = (int2*)take((size_t)nE * 8);
    int*   row32    = (int*)take((size_t)nE * 4);
    int*   col32    = (int*)take((size_t)nE * 4);
    int*   cnt      = (int*)take((size_t)nN * 4);
    int*   off      = (int*)take((size_t)nN * 4);
    int*   cursor   = (int*)take((size_t)nN * 4);
    float* dinv     = (float*)take((size_t)nN * 4);
    unsigned short* W1T = (unsigned short*)take((size_t)F * F * 2);
    int*   blockSum = (int*)take((size_t)nB * 4);

    w1t_kernel<<<F * F / 256, 256, 0, stream>>>(W1, W1T);
    convert_kernel<<<(nE + 255) / 256, 256, 0, stream>>>(ei, nE, batch, nN, row32, col32);
    hipMemsetAsync(cnt, 0, (size_t)nN * 4, stream);
    count_sliced_kernel<<<2048, 256, 0, stream>>>(col32, nE, nN, cnt);
    scanA_kernel<<<nB, 256, 0, stream>>>(cnt, nN, blockSum);
    scanB_kernel<<<1, 256, 0, stream>>>(blockSum, nB);
    scanC_kernel<<<nB, 256, 0, stream>>>(cnt, nN, blockSum, off, cursor, dinv);
    scatter_sliced_kernel<<<2048, 256, 0, stream>>>(row32, col32, nE, nN, dinv, cursor, csr);
    gemm1_mfma_kernel<<<(nN + 127) / 128, 256, 0, stream>>>(x, W1T, h_bf, nN);
    aggregate_kernel<<<(nN + 7) / 8, 256, 0, stream>>>(h_bf, csr, off, cnt, dinv, b1, agg_bf, nN);
    pool_final_kernel<<<N_GRAPHS, 256, 0, stream>>>(agg_bf, batch, nN, W2, b2, out);
}